// Round 10
// baseline (269.705 us; speedup 1.0000x reference)
//
#include <hip/hip_runtime.h>
#include <hip/hip_fp16.h>
#include <math.h>

#define N_NODES 50000
#define N_EDGES 800000
#define NFEAT 256
#define NHID 32
#define NHEADS 4
#define ALPHA 0.2f

#define BSH 5                               // 32 nodes per bucket
#define BNODES 32
#define NBUCK ((N_NODES + BNODES - 1) / BNODES)  // 1563
#define BCAP 704                            // mean 512 + 8.5 sigma

#define GEMM1_BLKS ((N_NODES + 63) / 64)   // 782
#define FILL_BLKS ((N_EDGES + 255) / 256)  // 3125

typedef _Float16 half8_t __attribute__((ext_vector_type(8)));
typedef float f32x4 __attribute__((ext_vector_type(4)));

__device__ __forceinline__ float elu_f(float x) {
    return x > 0.0f ? x : (__expf(x) - 1.0f);
}

// exp(leakyrelu(x)) — no max subtraction (scores O(1); softmax shift-invariant)
__device__ __forceinline__ float wexp(float x) {
    float l = x > 0.0f ? x : ALPHA * x;
    return __expf(l);
}

__device__ __forceinline__ float h2f_bits(unsigned wd, int sh) {
    ushort b = (ushort)(wd >> sh);
    return __half2float(*(__half*)&b);
}

// ---------- prep: Wt1/Wt2 fp16 transposed weights + zero bucket counters ----------
__global__ void k_prep(const float* __restrict__ Ws, const float* __restrict__ Wo,
                       ushort* __restrict__ Wt1, ushort* __restrict__ Wt2,
                       int* __restrict__ bcnt) {
    int idx = blockIdx.x * 256 + threadIdx.x;
    if (idx < 128 * 256) {
        int c = idx >> 8;
        int k = idx & 255;
        __half hv = __float2half(Ws[(c >> 5) * (NFEAT * NHID) + k * NHID + (c & 31)]);
        Wt1[idx] = *(ushort*)&hv;
    } else if (idx < 128 * 256 + 32 * 128) {
        int j = idx - 128 * 256;
        int c = j >> 7;
        int k = j & 127;
        __half hv = __float2half(Wo[k * NHID + c]);
        Wt2[j] = *(ushort*)&hv;
    }
    int z = idx - (128 * 256 + 32 * 128);
    if (z >= 0 && z < NBUCK) bcnt[z] = 0;
}

// ---------- MFMA GEMM body: C[nrows,N](fp16) = A[nrows,K] @ Wt^T, fused attn scalars ----------
template <int K, int NTILES, bool AHALF, int NH>
__device__ __forceinline__ void gemm_body(const void* __restrict__ Ain,
                                          const ushort* __restrict__ Wt,
                                          const float* __restrict__ attn,
                                          __half* __restrict__ C,
                                          float* __restrict__ So,
                                          float* __restrict__ Si,
                                          int nrows, int bid) {
    constexpr int N = NTILES * 16;
    constexpr int BK = 32;
    constexpr int LDB = 40;  // halves; 80B row stride -> 2-way LDS conflicts (free)

    __shared__ __align__(16) ushort Bs[N * LDB];

    int tid = threadIdx.x;
    int w = tid >> 6;
    int lane = tid & 63;
    int c = lane & 15;
    int quad = lane >> 4;
    int row0 = bid * 64 + w * 16;
    int gm = row0 + c;
    if (gm >= nrows) gm = nrows - 1;

    f32x4 acc[NTILES];
#pragma unroll
    for (int nt = 0; nt < NTILES; nt++)
#pragma unroll
        for (int i = 0; i < 4; i++) acc[nt][i] = 0.0f;

    float a_so[NTILES], a_si[NTILES];
#pragma unroll
    for (int nt = 0; nt < NTILES; nt++) {
        int h = nt >> 1;
        a_so[nt] = attn[h * 64 + (nt & 1) * 16 + c];
        a_si[nt] = attn[h * 64 + 32 + (nt & 1) * 16 + c];
    }

    for (int k0 = 0; k0 < K; k0 += BK) {
        if (tid < N * 2) {
            int r = tid >> 1;
            int part = tid & 1;
            const uint4* gp = (const uint4*)(Wt + (size_t)r * K + k0 + part * 16);
            uint4 v0 = gp[0];
            uint4 v1 = gp[1];
            uint4* lp = (uint4*)&Bs[r * LDB + part * 16];
            lp[0] = v0;
            lp[1] = v1;
        }
        __syncthreads();

        half8_t ahi, alo;
        if constexpr (AHALF) {
            ahi = *(const half8_t*)((const ushort*)Ain + (size_t)gm * K + k0 + quad * 8);
        } else {
            const float* ap = (const float*)Ain + (size_t)gm * K + k0 + quad * 8;
            float4 x0 = *(const float4*)ap;
            float4 x1 = *(const float4*)(ap + 4);
            float xa[8] = {x0.x, x0.y, x0.z, x0.w, x1.x, x1.y, x1.z, x1.w};
#pragma unroll
            for (int j = 0; j < 8; j++) {
                _Float16 h = (_Float16)xa[j];
                ahi[j] = h;
                alo[j] = (_Float16)(xa[j] - (float)h);
            }
        }
#pragma unroll
        for (int nt = 0; nt < NTILES; nt++) {
            half8_t b = *(const half8_t*)&Bs[(nt * 16 + c) * LDB + quad * 8];
            acc[nt] = __builtin_amdgcn_mfma_f32_16x16x32_f16(ahi, b, acc[nt], 0, 0, 0);
            if constexpr (!AHALF)
                acc[nt] = __builtin_amdgcn_mfma_f32_16x16x32_f16(alo, b, acc[nt], 0, 0, 0);
        }
        __syncthreads();
    }

#pragma unroll
    for (int reg = 0; reg < 4; reg++) {
        int ro = row0 + quad * 4 + reg;
        bool ok = ro < nrows;
        if (ok) {
#pragma unroll
            for (int nt = 0; nt < NTILES; nt++)
                C[(size_t)ro * N + nt * 16 + c] = __float2half(acc[nt][reg]);
        }
#pragma unroll
        for (int h = 0; h < NH; h++) {
            float so = acc[2 * h][reg] * a_so[2 * h] + acc[2 * h + 1][reg] * a_so[2 * h + 1];
            float si = acc[2 * h][reg] * a_si[2 * h] + acc[2 * h + 1][reg] * a_si[2 * h + 1];
            so += __shfl_xor(so, 1); si += __shfl_xor(si, 1);
            so += __shfl_xor(so, 2); si += __shfl_xor(si, 2);
            so += __shfl_xor(so, 4); si += __shfl_xor(si, 4);
            so += __shfl_xor(so, 8); si += __shfl_xor(si, 8);
            if (c == 0 && ok) {
                So[(size_t)ro * NH + h] = so;
                Si[(size_t)ro * NH + h] = si;
            }
        }
    }
}

// ---------- merged: GEMM-1 blocks + edge->bucket partition blocks ----------
__global__ __launch_bounds__(256) void k_g1fill(const float* __restrict__ x,
                                                const ushort* __restrict__ Wt1,
                                                const float* __restrict__ attn,
                                                __half* __restrict__ H1h,
                                                float* __restrict__ S1o,
                                                float* __restrict__ S1i,
                                                const int* __restrict__ src,
                                                const int* __restrict__ dst,
                                                int* __restrict__ bcnt,
                                                unsigned* __restrict__ bucket) {
    if (blockIdx.x < GEMM1_BLKS) {
        gemm_body<256, 8, false, 4>(x, Wt1, attn, H1h, S1o, S1i, N_NODES, blockIdx.x);
    } else {
        int e = (blockIdx.x - GEMM1_BLKS) * 256 + threadIdx.x;
        if (e < N_EDGES) {
            int s = src[e];
            int v = dst[e];
            int b = s >> BSH;
            int pos = atomicAdd(&bcnt[b], 1);
            if (pos < BCAP)
                bucket[(size_t)b * BCAP + pos] = ((unsigned)(s & (BNODES - 1)) << 16) | (unsigned)v;
        }
    }
}

// ---------- layer-2 GEMM ----------
__global__ __launch_bounds__(256) void k_gemm2(const __half* __restrict__ Hch,
                                               const ushort* __restrict__ Wt2,
                                               const float* __restrict__ attn,
                                               __half* __restrict__ H2h,
                                               float* __restrict__ S2o,
                                               float* __restrict__ S2i) {
    gemm_body<128, 2, true, 1>(Hch, Wt2, attn, H2h, S2o, S2i, N_NODES, blockIdx.x);
}

// ---------- shared mini-ELL build (32 nodes, in LDS) ----------
__device__ __forceinline__ int build_ell(const int* __restrict__ bcnt,
                                         const unsigned* __restrict__ bucket,
                                         int b, int* ldeg, ushort* ell_l) {
    int tid = threadIdx.x;
    if (tid < BNODES) ldeg[tid] = 0;
    __syncthreads();
    int cnt = bcnt[b];
    if (cnt > BCAP) cnt = BCAP;
    const unsigned* bp = bucket + (size_t)b * BCAP;
    for (int i = tid; i < cnt; i += 256) {
        unsigned e = bp[i];
        int sl = e >> 16;
        int v = (int)(e & 0xFFFFu);
        int slot = atomicAdd(&ldeg[sl], 1);
        if (slot < 64) ell_l[(sl << 6) + slot] = (ushort)v;
    }
    __syncthreads();
    return cnt;
}

// ---------- layer-1 aggregation: block = bucket; wave per node (8 rounds) ----------
__global__ __launch_bounds__(256) void k_agg1b(const int* __restrict__ bcnt,
                                               const unsigned* __restrict__ bucket,
                                               const float* __restrict__ S1o,
                                               const float* __restrict__ S1i,
                                               const __half* __restrict__ H1h,
                                               __half* __restrict__ Hch) {
    __shared__ int ldeg[BNODES];
    __shared__ ushort ell_l[BNODES * 64];
    __shared__ uint4 ew[4][64];
    int b = blockIdx.x;
    int base = b << BSH;
    build_ell(bcnt, bucket, b, ldeg, ell_l);

    int wv = threadIdx.x >> 6;
    int lane = threadIdx.x & 63;
    int sel = (lane >> 4) & 2;
    int sh = ((lane >> 4) & 1) * 16;
    const unsigned* Hp = (const unsigned*)H1h;

    for (int k = 0; k < 8; k++) {
        int idx = wv + (k << 2);
        int node = base + idx;
        if (node >= N_NODES) continue;
        int dg = ldeg[idx];
        if (dg > 64) dg = 64;
        // per-slot weights (lane = slot), wave-local LDS
        if (lane < dg) {
            int v = ell_l[(idx << 6) + lane];
            float4 so = *(const float4*)(S1o + 4 * (size_t)node);
            float4 si = *(const float4*)(S1i + 4 * (size_t)v);
            __half2 w01 = __floats2half2_rn(wexp(so.x + si.x), wexp(so.y + si.y));
            __half2 w23 = __floats2half2_rn(wexp(so.z + si.z), wexp(so.w + si.w));
            uint4 q;
            q.x = (unsigned)v;
            q.y = *(unsigned*)&w01;
            q.z = *(unsigned*)&w23;
            q.w = 0;
            ew[wv][lane] = q;
        }
        float a0 = 0.0f, a1 = 0.0f, d = 0.0f;
        int j = 0;
        for (; j + 3 < dg; j += 4) {
            uint4 q0 = ew[wv][j];
            uint4 q1 = ew[wv][j + 1];
            uint4 q2 = ew[wv][j + 2];
            uint4 q3 = ew[wv][j + 3];
            unsigned u0 = Hp[((size_t)q0.x << 6) + lane];
            unsigned u1 = Hp[((size_t)q1.x << 6) + lane];
            unsigned u2 = Hp[((size_t)q2.x << 6) + lane];
            unsigned u3 = Hp[((size_t)q3.x << 6) + lane];
            float w0 = h2f_bits(sel ? q0.z : q0.y, sh);
            float w1 = h2f_bits(sel ? q1.z : q1.y, sh);
            float w2 = h2f_bits(sel ? q2.z : q2.y, sh);
            float w3 = h2f_bits(sel ? q3.z : q3.y, sh);
            float2 h0 = __half22float2(*(__half2*)&u0);
            float2 h1 = __half22float2(*(__half2*)&u1);
            float2 h2 = __half22float2(*(__half2*)&u2);
            float2 h3 = __half22float2(*(__half2*)&u3);
            a0 += w0 * h0.x; a1 += w0 * h0.y; d += w0;
            a0 += w1 * h1.x; a1 += w1 * h1.y; d += w1;
            a0 += w2 * h2.x; a1 += w2 * h2.y; d += w2;
            a0 += w3 * h3.x; a1 += w3 * h3.y; d += w3;
        }
        for (; j < dg; j++) {
            uint4 q0 = ew[wv][j];
            unsigned u0 = Hp[((size_t)q0.x << 6) + lane];
            float w0 = h2f_bits(sel ? q0.z : q0.y, sh);
            float2 h0 = __half22float2(*(__half2*)&u0);
            a0 += w0 * h0.x; a1 += w0 * h0.y; d += w0;
        }
        float inv = d > 0.0f ? 1.0f / d : 0.0f;
        __half2 o = __floats2half2_rn(elu_f(a0 * inv), elu_f(a1 * inv));
        *(__half2*)(Hch + ((size_t)node << 7) + 2 * lane) = o;
    }
}

// ---------- layer-2 aggregation: block = bucket; 16-lane group per node (2 rounds) ----------
__global__ __launch_bounds__(256) void k_agg2b(const int* __restrict__ bcnt,
                                               const unsigned* __restrict__ bucket,
                                               const float* __restrict__ S2o,
                                               const float* __restrict__ S2i,
                                               const __half* __restrict__ H2h,
                                               float* __restrict__ out) {
    __shared__ int ldeg[BNODES];
    __shared__ ushort ell_l[BNODES * 64];
    __shared__ uint2 ew2[16][64];
    int b = blockIdx.x;
    int base = b << BSH;
    build_ell(bcnt, bucket, b, ldeg, ell_l);

    int grp = threadIdx.x >> 4;
    int l = threadIdx.x & 15;
    const unsigned* Hp = (const unsigned*)H2h;

    for (int k = 0; k < 2; k++) {
        int idx = grp + (k << 4);
        int node = base + idx;
        if (node >= N_NODES) continue;
        int dg = ldeg[idx];
        if (dg > 64) dg = 64;
        float so = S2o[node];
#pragma unroll
        for (int q = 0; q < 4; q++) {
            int j = l + (q << 4);
            if (j < dg) {
                int v = ell_l[(idx << 6) + j];
                float w = wexp(so + S2i[v]);
                uint2 qq;
                qq.x = (unsigned)v;
                qq.y = __float_as_uint(w);
                ew2[grp][j] = qq;
            }
        }
        float a0 = 0.0f, a1 = 0.0f, d = 0.0f;
        int j = 0;
        for (; j + 3 < dg; j += 4) {
            uint2 q0 = ew2[grp][j];
            uint2 q1 = ew2[grp][j + 1];
            uint2 q2 = ew2[grp][j + 2];
            uint2 q3 = ew2[grp][j + 3];
            unsigned u0 = Hp[((size_t)q0.x << 4) + l];
            unsigned u1 = Hp[((size_t)q1.x << 4) + l];
            unsigned u2 = Hp[((size_t)q2.x << 4) + l];
            unsigned u3 = Hp[((size_t)q3.x << 4) + l];
            float w0 = __uint_as_float(q0.y);
            float w1 = __uint_as_float(q1.y);
            float w2 = __uint_as_float(q2.y);
            float w3 = __uint_as_float(q3.y);
            float2 h0 = __half22float2(*(__half2*)&u0);
            float2 h1 = __half22float2(*(__half2*)&u1);
            float2 h2 = __half22float2(*(__half2*)&u2);
            float2 h3 = __half22float2(*(__half2*)&u3);
            a0 += w0 * h0.x; a1 += w0 * h0.y; d += w0;
            a0 += w1 * h1.x; a1 += w1 * h1.y; d += w1;
            a0 += w2 * h2.x; a1 += w2 * h2.y; d += w2;
            a0 += w3 * h3.x; a1 += w3 * h3.y; d += w3;
        }
        for (; j < dg; j++) {
            uint2 q0 = ew2[grp][j];
            unsigned u0 = Hp[((size_t)q0.x << 4) + l];
            float w0 = __uint_as_float(q0.y);
            float2 h0 = __half22float2(*(__half2*)&u0);
            a0 += w0 * h0.x; a1 += w0 * h0.y; d += w0;
        }
        float inv = d > 0.0f ? 1.0f / d : 0.0f;
        float2 o = make_float2(elu_f(a0 * inv), elu_f(a1 * inv));
        *(float2*)(out + ((size_t)node << 5) + 2 * l) = o;
    }
}

extern "C" void kernel_launch(void* const* d_in, const int* in_sizes, int n_in,
                              void* d_out, int out_size, void* d_ws, size_t ws_size,
                              hipStream_t stream) {
    const float* x = (const float*)d_in[0];
    const int* src = (const int*)d_in[1];
    const int* dst = (const int*)d_in[2];
    const float* Ws = (const float*)d_in[3];
    const float* As = (const float*)d_in[4];
    const float* Wo = (const float*)d_in[5];
    const float* Ao = (const float*)d_in[6];
    float* out = (float*)d_out;

    char* p = (char*)d_ws;
    auto alloc = [&](size_t bytes) -> void* {
        void* r = (void*)p;
        p += (bytes + 255) & ~(size_t)255;
        return r;
    };
    ushort* Wt1 = (ushort*)alloc((size_t)128 * 256 * 2);
    ushort* Wt2 = (ushort*)alloc((size_t)32 * 128 * 2);
    __half* H1h = (__half*)alloc((size_t)N_NODES * 128 * 2);   // 12.8 MB
    __half* Hch = (__half*)alloc((size_t)N_NODES * 128 * 2);   // 12.8 MB
    __half* H2h = (__half*)alloc((size_t)N_NODES * 32 * 2);    // 3.2 MB
    float* S1o = (float*)alloc((size_t)N_NODES * 4 * 4);
    float* S1i = (float*)alloc((size_t)N_NODES * 4 * 4);
    float* S2o = (float*)alloc((size_t)N_NODES * 4);
    float* S2i = (float*)alloc((size_t)N_NODES * 4);
    int* bcnt = (int*)alloc((size_t)NBUCK * 4);
    unsigned* bucket = (unsigned*)alloc((size_t)NBUCK * BCAP * 4);  // 4.4 MB

    // 1) weight transform + zero bucket counters
    const int PREP_THREADS = 128 * 256 + 32 * 128 + NBUCK;
    k_prep<<<(PREP_THREADS + 255) / 256, 256, 0, stream>>>(Ws, Wo, Wt1, Wt2, bcnt);

    // 2) layer-1 GEMM (MFMA) merged with edge->bucket partition
    k_g1fill<<<GEMM1_BLKS + FILL_BLKS, 256, 0, stream>>>(
        x, Wt1, As, H1h, S1o, S1i, src, dst, bcnt, bucket);

    // 3) layer-1 aggregation (bucket -> LDS mini-ELL -> gather)
    k_agg1b<<<NBUCK, 256, 0, stream>>>(bcnt, bucket, S1o, S1i, H1h, Hch);

    // 4) layer-2 GEMM
    k_gemm2<<<(N_NODES + 63) / 64, 256, 0, stream>>>(Hch, Wt2, Ao, H2h, S2o, S2i);

    // 5) layer-2 aggregation
    k_agg2b<<<NBUCK, 256, 0, stream>>>(bcnt, bucket, S2o, S2i, H2h, out);
}

// Round 11
// 201.765 us; speedup vs baseline: 1.3367x; 1.3367x over previous
//
#include <hip/hip_runtime.h>
#include <hip/hip_fp16.h>
#include <math.h>

#define N_NODES 50000
#define N_EDGES 800000
#define NFEAT 256
#define NHID 32
#define NHEADS 4
#define ALPHA 0.2f
#define ELLCAP 62   // slots per node; row = [int deg][62 ushort] = 128 B

#define GEMM1_BLKS ((N_NODES + 63) / 64)   // 782
#define FILL_BLKS ((N_EDGES + 255) / 256)  // 3125

typedef _Float16 half8_t __attribute__((ext_vector_type(8)));
typedef float f32x4 __attribute__((ext_vector_type(4)));

__device__ __forceinline__ float elu_f(float x) {
    return x > 0.0f ? x : (__expf(x) - 1.0f);
}

// exp(leakyrelu(x)) — no max subtraction (scores O(1); softmax shift-invariant)
__device__ __forceinline__ float wexp(float x) {
    float l = x > 0.0f ? x : ALPHA * x;
    return __expf(l);
}

__device__ __forceinline__ float h2f_bits(unsigned wd, int sh) {
    ushort b = (ushort)(wd >> sh);
    return __half2float(*(__half*)&b);
}

// ---------- prep: Wt1/Wt2 fp16 transposed weights + zero embedded deg counters ----------
__global__ void k_prep(const float* __restrict__ Ws, const float* __restrict__ Wo,
                       ushort* __restrict__ Wt1, ushort* __restrict__ Wt2,
                       char* __restrict__ ell) {
    int idx = blockIdx.x * 256 + threadIdx.x;
    if (idx < 128 * 256) {
        int c = idx >> 8;
        int k = idx & 255;
        __half hv = __float2half(Ws[(c >> 5) * (NFEAT * NHID) + k * NHID + (c & 31)]);
        Wt1[idx] = *(ushort*)&hv;
    } else if (idx < 128 * 256 + 32 * 128) {
        int j = idx - 128 * 256;
        int c = j >> 7;
        int k = j & 127;
        __half hv = __float2half(Wo[k * NHID + c]);
        Wt2[j] = *(ushort*)&hv;
    }
    int z = idx - (128 * 256 + 32 * 128);
    if (z >= 0 && z < N_NODES) *(int*)(ell + ((size_t)z << 7)) = 0;
}

// ---------- MFMA GEMM body: C[nrows,N](fp16) = A[nrows,K] @ Wt^T, fused attn scalars ----------
template <int K, int NTILES, bool AHALF, int NH>
__device__ __forceinline__ void gemm_body(const void* __restrict__ Ain,
                                          const ushort* __restrict__ Wt,
                                          const float* __restrict__ attn,
                                          __half* __restrict__ C,
                                          float* __restrict__ So,
                                          float* __restrict__ Si,
                                          int nrows, int bid) {
    constexpr int N = NTILES * 16;
    constexpr int BK = 32;
    constexpr int LDB = 40;  // halves; 80B row stride -> 2-way LDS conflicts (free)

    __shared__ __align__(16) ushort Bs[N * LDB];

    int tid = threadIdx.x;
    int w = tid >> 6;
    int lane = tid & 63;
    int c = lane & 15;
    int quad = lane >> 4;
    int row0 = bid * 64 + w * 16;
    int gm = row0 + c;
    if (gm >= nrows) gm = nrows - 1;

    f32x4 acc[NTILES];
#pragma unroll
    for (int nt = 0; nt < NTILES; nt++)
#pragma unroll
        for (int i = 0; i < 4; i++) acc[nt][i] = 0.0f;

    float a_so[NTILES], a_si[NTILES];
#pragma unroll
    for (int nt = 0; nt < NTILES; nt++) {
        int h = nt >> 1;
        a_so[nt] = attn[h * 64 + (nt & 1) * 16 + c];
        a_si[nt] = attn[h * 64 + 32 + (nt & 1) * 16 + c];
    }

    for (int k0 = 0; k0 < K; k0 += BK) {
        if (tid < N * 2) {
            int r = tid >> 1;
            int part = tid & 1;
            const uint4* gp = (const uint4*)(Wt + (size_t)r * K + k0 + part * 16);
            uint4 v0 = gp[0];
            uint4 v1 = gp[1];
            uint4* lp = (uint4*)&Bs[r * LDB + part * 16];
            lp[0] = v0;
            lp[1] = v1;
        }
        __syncthreads();

        half8_t ahi, alo;
        if constexpr (AHALF) {
            ahi = *(const half8_t*)((const ushort*)Ain + (size_t)gm * K + k0 + quad * 8);
        } else {
            const float* ap = (const float*)Ain + (size_t)gm * K + k0 + quad * 8;
            float4 x0 = *(const float4*)ap;
            float4 x1 = *(const float4*)(ap + 4);
            float xa[8] = {x0.x, x0.y, x0.z, x0.w, x1.x, x1.y, x1.z, x1.w};
#pragma unroll
            for (int j = 0; j < 8; j++) {
                _Float16 h = (_Float16)xa[j];
                ahi[j] = h;
                alo[j] = (_Float16)(xa[j] - (float)h);
            }
        }
#pragma unroll
        for (int nt = 0; nt < NTILES; nt++) {
            half8_t b = *(const half8_t*)&Bs[(nt * 16 + c) * LDB + quad * 8];
            acc[nt] = __builtin_amdgcn_mfma_f32_16x16x32_f16(ahi, b, acc[nt], 0, 0, 0);
            if constexpr (!AHALF)
                acc[nt] = __builtin_amdgcn_mfma_f32_16x16x32_f16(alo, b, acc[nt], 0, 0, 0);
        }
        __syncthreads();
    }

#pragma unroll
    for (int reg = 0; reg < 4; reg++) {
        int ro = row0 + quad * 4 + reg;
        bool ok = ro < nrows;
        if (ok) {
#pragma unroll
            for (int nt = 0; nt < NTILES; nt++)
                C[(size_t)ro * N + nt * 16 + c] = __float2half(acc[nt][reg]);
        }
#pragma unroll
        for (int h = 0; h < NH; h++) {
            float so = acc[2 * h][reg] * a_so[2 * h] + acc[2 * h + 1][reg] * a_so[2 * h + 1];
            float si = acc[2 * h][reg] * a_si[2 * h] + acc[2 * h + 1][reg] * a_si[2 * h + 1];
            so += __shfl_xor(so, 1); si += __shfl_xor(si, 1);
            so += __shfl_xor(so, 2); si += __shfl_xor(si, 2);
            so += __shfl_xor(so, 4); si += __shfl_xor(si, 4);
            so += __shfl_xor(so, 8); si += __shfl_xor(si, 8);
            if (c == 0 && ok) {
                So[(size_t)ro * NH + h] = so;
                Si[(size_t)ro * NH + h] = si;
            }
        }
    }
}

// ---------- merged: GEMM-1 blocks + ELL-fill blocks (deg embedded in row line) ----------
__global__ __launch_bounds__(256) void k_g1fill(const float* __restrict__ x,
                                                const ushort* __restrict__ Wt1,
                                                const float* __restrict__ attn,
                                                __half* __restrict__ H1h,
                                                float* __restrict__ S1o,
                                                float* __restrict__ S1i,
                                                const int* __restrict__ src,
                                                const int* __restrict__ dst,
                                                char* __restrict__ ell) {
    if (blockIdx.x < GEMM1_BLKS) {
        gemm_body<256, 8, false, 4>(x, Wt1, attn, H1h, S1o, S1i, N_NODES, blockIdx.x);
    } else {
        int e = (blockIdx.x - GEMM1_BLKS) * 256 + threadIdx.x;
        if (e < N_EDGES) {
            int s = src[e];
            int v = dst[e];
            char* row = ell + ((size_t)s << 7);
            int slot = atomicAdd((int*)row, 1);
            if (slot < ELLCAP) *(ushort*)(row + 4 + 2 * slot) = (ushort)v;
        }
    }
}

// ---------- layer-2 GEMM ----------
__global__ __launch_bounds__(256) void k_gemm2(const __half* __restrict__ Hch,
                                               const ushort* __restrict__ Wt2,
                                               const float* __restrict__ attn,
                                               __half* __restrict__ H2h,
                                               float* __restrict__ S2o,
                                               float* __restrict__ S2i) {
    gemm_body<128, 2, true, 1>(Hch, Wt2, attn, H2h, S2o, S2i, N_NODES, blockIdx.x);
}

// ---------- layer-1 aggregation: wave/node; weights in prologue -> LDS; unroll-8 gathers ----------
__global__ __launch_bounds__(256) void k_aggw4(const char* __restrict__ ell,
                                               const float* __restrict__ S1o,
                                               const float* __restrict__ S1i,
                                               const __half* __restrict__ H1h,
                                               __half* __restrict__ Hch) {
    __shared__ uint4 ew[4][64];  // {dst, w01, w23, pad} per slot, per wave
    int wv = threadIdx.x >> 6;
    int node = blockIdx.x * 4 + wv;  // grid exact: 12500*4 == 50000
    int lane = threadIdx.x & 63;
    const char* row = ell + ((size_t)node << 7);
    int dg = *(const int*)row;
    if (dg > ELLCAP) dg = ELLCAP;
    // prologue: lane j computes slot j's 4 head weights
    if (lane < dg) {
        int v = *(const ushort*)(row + 4 + 2 * lane);
        float4 so = *(const float4*)(S1o + 4 * (size_t)node);
        float4 si = *(const float4*)(S1i + 4 * (size_t)v);
        __half2 w01 = __floats2half2_rn(wexp(so.x + si.x), wexp(so.y + si.y));
        __half2 w23 = __floats2half2_rn(wexp(so.z + si.z), wexp(so.w + si.w));
        uint4 q;
        q.x = (unsigned)v;
        q.y = *(unsigned*)&w01;
        q.z = *(unsigned*)&w23;
        q.w = 0;
        ew[wv][lane] = q;
    }
    __syncthreads();
    int sel = (lane >> 4) & 2;
    int sh = ((lane >> 4) & 1) * 16;
    const unsigned* Hp = (const unsigned*)H1h;
    float a0 = 0.0f, a1 = 0.0f, d = 0.0f;
    int j = 0;
    for (; j + 7 < dg; j += 8) {
        uint4 q0 = ew[wv][j];
        uint4 q1 = ew[wv][j + 1];
        uint4 q2 = ew[wv][j + 2];
        uint4 q3 = ew[wv][j + 3];
        uint4 q4 = ew[wv][j + 4];
        uint4 q5 = ew[wv][j + 5];
        uint4 q6 = ew[wv][j + 6];
        uint4 q7 = ew[wv][j + 7];
        unsigned u0 = Hp[((size_t)q0.x << 6) + lane];
        unsigned u1 = Hp[((size_t)q1.x << 6) + lane];
        unsigned u2 = Hp[((size_t)q2.x << 6) + lane];
        unsigned u3 = Hp[((size_t)q3.x << 6) + lane];
        unsigned u4 = Hp[((size_t)q4.x << 6) + lane];
        unsigned u5 = Hp[((size_t)q5.x << 6) + lane];
        unsigned u6 = Hp[((size_t)q6.x << 6) + lane];
        unsigned u7 = Hp[((size_t)q7.x << 6) + lane];
        float w0 = h2f_bits(sel ? q0.z : q0.y, sh);
        float w1 = h2f_bits(sel ? q1.z : q1.y, sh);
        float w2 = h2f_bits(sel ? q2.z : q2.y, sh);
        float w3 = h2f_bits(sel ? q3.z : q3.y, sh);
        float w4 = h2f_bits(sel ? q4.z : q4.y, sh);
        float w5 = h2f_bits(sel ? q5.z : q5.y, sh);
        float w6 = h2f_bits(sel ? q6.z : q6.y, sh);
        float w7 = h2f_bits(sel ? q7.z : q7.y, sh);
        float2 h0 = __half22float2(*(__half2*)&u0);
        float2 h1 = __half22float2(*(__half2*)&u1);
        float2 h2 = __half22float2(*(__half2*)&u2);
        float2 h3 = __half22float2(*(__half2*)&u3);
        float2 h4 = __half22float2(*(__half2*)&u4);
        float2 h5 = __half22float2(*(__half2*)&u5);
        float2 h6 = __half22float2(*(__half2*)&u6);
        float2 h7 = __half22float2(*(__half2*)&u7);
        a0 += w0 * h0.x; a1 += w0 * h0.y; d += w0;
        a0 += w1 * h1.x; a1 += w1 * h1.y; d += w1;
        a0 += w2 * h2.x; a1 += w2 * h2.y; d += w2;
        a0 += w3 * h3.x; a1 += w3 * h3.y; d += w3;
        a0 += w4 * h4.x; a1 += w4 * h4.y; d += w4;
        a0 += w5 * h5.x; a1 += w5 * h5.y; d += w5;
        a0 += w6 * h6.x; a1 += w6 * h6.y; d += w6;
        a0 += w7 * h7.x; a1 += w7 * h7.y; d += w7;
    }
    for (; j + 3 < dg; j += 4) {
        uint4 q0 = ew[wv][j];
        uint4 q1 = ew[wv][j + 1];
        uint4 q2 = ew[wv][j + 2];
        uint4 q3 = ew[wv][j + 3];
        unsigned u0 = Hp[((size_t)q0.x << 6) + lane];
        unsigned u1 = Hp[((size_t)q1.x << 6) + lane];
        unsigned u2 = Hp[((size_t)q2.x << 6) + lane];
        unsigned u3 = Hp[((size_t)q3.x << 6) + lane];
        float w0 = h2f_bits(sel ? q0.z : q0.y, sh);
        float w1 = h2f_bits(sel ? q1.z : q1.y, sh);
        float w2 = h2f_bits(sel ? q2.z : q2.y, sh);
        float w3 = h2f_bits(sel ? q3.z : q3.y, sh);
        float2 h0 = __half22float2(*(__half2*)&u0);
        float2 h1 = __half22float2(*(__half2*)&u1);
        float2 h2 = __half22float2(*(__half2*)&u2);
        float2 h3 = __half22float2(*(__half2*)&u3);
        a0 += w0 * h0.x; a1 += w0 * h0.y; d += w0;
        a0 += w1 * h1.x; a1 += w1 * h1.y; d += w1;
        a0 += w2 * h2.x; a1 += w2 * h2.y; d += w2;
        a0 += w3 * h3.x; a1 += w3 * h3.y; d += w3;
    }
    for (; j < dg; j++) {
        uint4 q0 = ew[wv][j];
        unsigned u0 = Hp[((size_t)q0.x << 6) + lane];
        float w0 = h2f_bits(sel ? q0.z : q0.y, sh);
        float2 h0 = __half22float2(*(__half2*)&u0);
        a0 += w0 * h0.x; a1 += w0 * h0.y; d += w0;
    }
    float inv = d > 0.0f ? 1.0f / d : 0.0f;
    __half2 o = __floats2half2_rn(elu_f(a0 * inv), elu_f(a1 * inv));
    *(__half2*)(Hch + ((size_t)node << 7) + 2 * lane) = o;
}

// ---------- layer-2 aggregation: 16 lanes/node; weights in prologue -> LDS ----------
__global__ __launch_bounds__(256) void k_aggw2(const char* __restrict__ ell,
                                               const float* __restrict__ S2o,
                                               const float* __restrict__ S2i,
                                               const __half* __restrict__ H2h,
                                               float* __restrict__ out) {
    __shared__ uint2 ew[16][64];  // {dst, w f32} per slot, 16 nodes/block
    int t = blockIdx.x * 256 + threadIdx.x;
    int node = t >> 4;  // grid exact: 3125*256/16 == 50000
    int ng = (threadIdx.x >> 4);
    int l = t & 15;
    const char* row = ell + ((size_t)node << 7);
    int dg = *(const int*)row;
    if (dg > ELLCAP) dg = ELLCAP;
    float so = S2o[node];
#pragma unroll
    for (int k = 0; k < 4; k++) {
        int j = l + k * 16;
        if (j < dg) {
            int v = *(const ushort*)(row + 4 + 2 * j);
            float w = wexp(so + S2i[v]);
            uint2 q;
            q.x = (unsigned)v;
            q.y = __float_as_uint(w);
            ew[ng][j] = q;
        }
    }
    __syncthreads();
    const unsigned* Hp = (const unsigned*)H2h;
    float a0 = 0.0f, a1 = 0.0f, d = 0.0f;
    int j = 0;
    for (; j + 3 < dg; j += 4) {
        uint2 q0 = ew[ng][j];
        uint2 q1 = ew[ng][j + 1];
        uint2 q2 = ew[ng][j + 2];
        uint2 q3 = ew[ng][j + 3];
        unsigned u0 = Hp[((size_t)q0.x << 4) + l];
        unsigned u1 = Hp[((size_t)q1.x << 4) + l];
        unsigned u2 = Hp[((size_t)q2.x << 4) + l];
        unsigned u3 = Hp[((size_t)q3.x << 4) + l];
        float w0 = __uint_as_float(q0.y);
        float w1 = __uint_as_float(q1.y);
        float w2 = __uint_as_float(q2.y);
        float w3 = __uint_as_float(q3.y);
        float2 h0 = __half22float2(*(__half2*)&u0);
        float2 h1 = __half22float2(*(__half2*)&u1);
        float2 h2 = __half22float2(*(__half2*)&u2);
        float2 h3 = __half22float2(*(__half2*)&u3);
        a0 += w0 * h0.x; a1 += w0 * h0.y; d += w0;
        a0 += w1 * h1.x; a1 += w1 * h1.y; d += w1;
        a0 += w2 * h2.x; a1 += w2 * h2.y; d += w2;
        a0 += w3 * h3.x; a1 += w3 * h3.y; d += w3;
    }
    for (; j < dg; j++) {
        uint2 q0 = ew[ng][j];
        unsigned u0 = Hp[((size_t)q0.x << 4) + l];
        float w0 = __uint_as_float(q0.y);
        float2 h0 = __half22float2(*(__half2*)&u0);
        a0 += w0 * h0.x; a1 += w0 * h0.y; d += w0;
    }
    float inv = d > 0.0f ? 1.0f / d : 0.0f;
    float2 o = make_float2(elu_f(a0 * inv), elu_f(a1 * inv));
    *(float2*)(out + ((size_t)node << 5) + 2 * l) = o;
}

extern "C" void kernel_launch(void* const* d_in, const int* in_sizes, int n_in,
                              void* d_out, int out_size, void* d_ws, size_t ws_size,
                              hipStream_t stream) {
    const float* x = (const float*)d_in[0];
    const int* src = (const int*)d_in[1];
    const int* dst = (const int*)d_in[2];
    const float* Ws = (const float*)d_in[3];
    const float* As = (const float*)d_in[4];
    const float* Wo = (const float*)d_in[5];
    const float* Ao = (const float*)d_in[6];
    float* out = (float*)d_out;

    char* p = (char*)d_ws;
    auto alloc = [&](size_t bytes) -> void* {
        void* r = (void*)p;
        p += (bytes + 255) & ~(size_t)255;
        return r;
    };
    ushort* Wt1 = (ushort*)alloc((size_t)128 * 256 * 2);
    ushort* Wt2 = (ushort*)alloc((size_t)32 * 128 * 2);
    __half* H1h = (__half*)alloc((size_t)N_NODES * 128 * 2);   // 12.8 MB
    __half* Hch = (__half*)alloc((size_t)N_NODES * 128 * 2);   // 12.8 MB
    __half* H2h = (__half*)alloc((size_t)N_NODES * 32 * 2);    // 3.2 MB
    float* S1o = (float*)alloc((size_t)N_NODES * 4 * 4);
    float* S1i = (float*)alloc((size_t)N_NODES * 4 * 4);
    float* S2o = (float*)alloc((size_t)N_NODES * 4);
    float* S2i = (float*)alloc((size_t)N_NODES * 4);
    char* ell  = (char*)alloc((size_t)N_NODES * 128);          // 6.4 MB packed rows

    // 1) weight transform + zero embedded deg
    const int PREP_THREADS = 128 * 256 + 32 * 128 + N_NODES;
    k_prep<<<(PREP_THREADS + 255) / 256, 256, 0, stream>>>(Ws, Wo, Wt1, Wt2, ell);

    // 2) layer-1 GEMM (MFMA, hi/lo split) merged with ELL build
    k_g1fill<<<GEMM1_BLKS + FILL_BLKS, 256, 0, stream>>>(
        x, Wt1, As, H1h, S1o, S1i, src, dst, ell);

    // 3) layer-1 aggregation (weights in prologue, unroll-8 gathers)
    k_aggw4<<<(N_NODES + 3) / 4, 256, 0, stream>>>(ell, S1o, S1i, H1h, Hch);

    // 4) layer-2 GEMM
    k_gemm2<<<(N_NODES + 63) / 64, 256, 0, stream>>>(Hch, Wt2, Ao, H2h, S2o, S2i);

    // 5) layer-2 aggregation
    k_aggw2<<<(N_NODES * 16 + 255) / 256, 256, 0, stream>>>(ell, S2o, S2i, H2h, out);
}